// Round 6
// baseline (772.261 us; speedup 1.0000x reference)
//
#include <hip/hip_runtime.h>
#include <cstdint>
#include <cstddef>

// PureCartesianTensorProduct: B=4096, C1=C2=COUT=64, LMAX=2, FEAT=832, 15 paths.
// out[z,c,m] = sum_p sum_ab W_p[c,a,b] * T_p,m[z,a,b].
// MFMA f32_32x32x16_f16. A = W pre-swizzled in A-frag order (global, L2-hot,
// 2-deep even/odd register prefetch). Wave = 1 z-group x 2 c-group accumulators
// sharing one tb. x2: coalesced LDS stage -> a-invariant regs (ds_read_b128).
// x1: f16 transposed LDS tile (stride 66), scalar per (a,z), prefetched.
// K-split x2 across blockIdx.z by chunk parity; f32 atomicAdd epilogue into
// zero-initialized out. No barriers inside the a-loop.

#define FEAT 832
#define ZT 64

typedef _Float16 half8 __attribute__((ext_vector_type(8)));
typedef float floatx16 __attribute__((ext_vector_type(16)));

struct Chunk {
  int wbase;      // p * 262144, element offset into swizzled f16 weight
  int o1[3];      // absolute x1 feature offset for term t (at a=0)
  int o2[3];      // absolute x2 feature offset for term t (at b=0)
  float sg[3];    // +-1
  int d1, d2, nt; // a-stride (3^L1), b-stride (3^L2), #terms (<=3)
};

// Swizzle W f32 [p][c][k] -> f16 A-frag order:
// Wsw[((p*256 + ksg)*2 + cgrp)*512 + lane*8 + j] = W_p[cgrp*32+(lane&31)][ksg*16+(lane>>5)*8+j]
__global__ void swz_w_kernel(const float* __restrict__ w, _Float16* __restrict__ o) {
  const int i = blockIdx.x * 256 + threadIdx.x;     // one half8 chunk per thread
  const int lane = i & 63;
  const int pkc  = i >> 6;
  const int cgrp = pkc & 1;
  const int ksg  = (pkc >> 1) & 255;
  const int p    = pkc >> 9;
  const int c  = cgrp * 32 + (lane & 31);
  const int k0 = ksg * 16 + (lane >> 5) * 8;
  const float* src = w + (size_t)p * 262144 + (size_t)c * 4096 + k0;
  const float4 v0 = *(const float4*)(src);
  const float4 v1 = *(const float4*)(src + 4);
  half8 h = { (_Float16)v0.x, (_Float16)v0.y, (_Float16)v0.z, (_Float16)v0.w,
              (_Float16)v1.x, (_Float16)v1.y, (_Float16)v1.z, (_Float16)v1.w };
  *(half8*)(o + (size_t)i * 8) = h;
}

__global__ void zero_out_kernel(float4* __restrict__ o, int n4) {
  const int i = blockIdx.x * 256 + threadIdx.x;
  if (i < n4) o[i] = float4{0.f, 0.f, 0.f, 0.f};
}

__device__ __forceinline__ half8 splat8(_Float16 h) {
  return half8{h, h, h, h, h, h, h, h};
}

// XS union: X2 view [t][zz]*72+b (13824 max idx); X1 view [t][a]*66+zz (12670 max).
template<int NT>
__device__ __forceinline__ void run_chunk(
    const Chunk C, const int zbase, const int zl, const int hf,
    const int lane, const int tid,
    const float* __restrict__ x1, const float* __restrict__ x2,
    const _Float16* __restrict__ Wh, _Float16* __restrict__ XS,
    floatx16& acc0, floatx16& acc1)
{
  __syncthreads();  // previous chunk's X1-view readers done

  // stage x2 tile coalesced: XS[(t*64+zz)*72+b] = (f16) x2[zbase+zz, o2[t]+b*d2]
  #pragma unroll
  for (int t = 0; t < NT; ++t) {
    const size_t base2 = (size_t)zbase * FEAT + C.o2[t];
    for (int e = tid; e < 4096; e += 128) {
      const int zz = e >> 6, b = e & 63;
      XS[(t * 64 + zz) * 72 + b] =
          (_Float16)x2[base2 + (size_t)zz * FEAT + b * C.d2];
    }
  }
  __syncthreads();

  // a-invariant x2 register fragments (ds_read_b128)
  half8 x2r[NT][4];
  #pragma unroll
  for (int t = 0; t < NT; ++t) {
    #pragma unroll
    for (int ks = 0; ks < 4; ++ks)
      x2r[t][ks] = *(const half8*)&XS[(t * 64 + zl) * 72 + ks * 16 + hf * 8];
  }
  __syncthreads();  // all x2-view reads done before X1 writes

  // stage x1 transposed [t][a][z] stride 66 (33 dwords -> conflict-free), sign folded
  #pragma unroll
  for (int t = 0; t < NT; ++t) {
    const float sgf = C.sg[t];
    const int o1 = C.o1[t];
    for (int e = tid; e < 4096; e += 128) {
      const int a = e & 63, zz = e >> 6;
      XS[(t * 64 + a) * 66 + zz] =
          (_Float16)(x1[(size_t)(zbase + zz) * FEAT + o1 + a * C.d1] * sgf);
    }
  }
  __syncthreads();

  const _Float16* __restrict__ Wq = Wh + C.wbase + lane * 8;
  const _Float16* __restrict__ Xq = XS + zl;

  // 2-deep W prefetch: even/odd a buffers, [cgrp][ks]
  half8 afE[2][4], afO[2][4];
  #pragma unroll
  for (int ks = 0; ks < 4; ++ks) {
    afE[0][ks] = *(const half8*)(Wq + ks * 1024);
    afE[1][ks] = *(const half8*)(Wq + ks * 1024 + 512);
    afO[0][ks] = *(const half8*)(Wq + 4096 + ks * 1024);
    afO[1][ks] = *(const half8*)(Wq + 4096 + ks * 1024 + 512);
  }
  _Float16 sc[NT], scn[NT];
  #pragma unroll
  for (int t = 0; t < NT; ++t) {
    sc[t]  = Xq[(t * 64 + 0) * 66];
    scn[t] = Xq[(t * 64 + 1) * 66];
  }

  #pragma unroll 1
  for (int a = 0; a < 64; a += 2) {
    {  // even: compute a, prefetch a+2
      half8 sv[NT];
      #pragma unroll
      for (int t = 0; t < NT; ++t) sv[t] = splat8(sc[t]);
      if (a + 2 < 64) {
        #pragma unroll
        for (int t = 0; t < NT; ++t) sc[t] = Xq[(t * 64 + a + 2) * 66];
      }
      #pragma unroll
      for (int ks = 0; ks < 4; ++ks) {
        half8 tb = sv[0] * x2r[0][ks];
        if (NT > 1) tb += sv[1] * x2r[1][ks];
        if (NT > 2) tb += sv[2] * x2r[2][ks];
        acc0 = __builtin_amdgcn_mfma_f32_32x32x16_f16(afE[0][ks], tb, acc0, 0, 0, 0);
        acc1 = __builtin_amdgcn_mfma_f32_32x32x16_f16(afE[1][ks], tb, acc1, 0, 0, 0);
      }
      if (a + 2 < 64) {
        const _Float16* wn = Wq + (a + 2) * 4096;
        #pragma unroll
        for (int ks = 0; ks < 4; ++ks) {
          afE[0][ks] = *(const half8*)(wn + ks * 1024);
          afE[1][ks] = *(const half8*)(wn + ks * 1024 + 512);
        }
      }
    }
    {  // odd: compute a+1, prefetch a+3
      half8 sv[NT];
      #pragma unroll
      for (int t = 0; t < NT; ++t) sv[t] = splat8(scn[t]);
      if (a + 3 < 64) {
        #pragma unroll
        for (int t = 0; t < NT; ++t) scn[t] = Xq[(t * 64 + a + 3) * 66];
      }
      #pragma unroll
      for (int ks = 0; ks < 4; ++ks) {
        half8 tb = sv[0] * x2r[0][ks];
        if (NT > 1) tb += sv[1] * x2r[1][ks];
        if (NT > 2) tb += sv[2] * x2r[2][ks];
        acc0 = __builtin_amdgcn_mfma_f32_32x32x16_f16(afO[0][ks], tb, acc0, 0, 0, 0);
        acc1 = __builtin_amdgcn_mfma_f32_32x32x16_f16(afO[1][ks], tb, acc1, 0, 0, 0);
      }
      if (a + 3 < 64) {
        const _Float16* wn = Wq + (a + 3) * 4096;
        #pragma unroll
        for (int ks = 0; ks < 4; ++ks) {
          afO[0][ks] = *(const half8*)(wn + ks * 1024);
          afO[1][ks] = *(const half8*)(wn + ks * 1024 + 512);
        }
      }
    }
  }
}

__global__ __launch_bounds__(128, 3) void tp_kernel(
    const float* __restrict__ x1, const float* __restrict__ x2,
    const _Float16* __restrict__ Wh, float* __restrict__ out)
{
  __shared__ __align__(16) _Float16 XS[3 * 64 * 72]; // 27648 B union (X2/X1 views)
  __shared__ Chunk chs[7];
  __shared__ int nch_s;

  const int tid  = threadIdx.x;
  const int slot = blockIdx.y;           // 0: L0; 1..3: L1 m; 4..12: L2 (u,v)
  const int half = blockIdx.z;           // K-split: chunk parity
  const int zbase = blockIdx.x * ZT;
  const int zgrp = tid >> 6;             // wave = z-group
  const int lane = tid & 63;
  const int ln31 = lane & 31;
  const int hf   = lane >> 5;
  const int zl   = zgrp * 32 + ln31;     // B-frag col z within tile

  int offO, dO, mO;
  if (slot == 0)      { offO = 0;   dO = 1; mO = 0; }
  else if (slot < 4)  { offO = 64;  dO = 3; mO = slot - 1; }
  else                { offO = 256; dO = 9; mO = slot - 4; }

  if (tid == 0) {
    int n = 0;
    auto add = [&](int p, int L1, int L2,
                   int i0, int i1, int i2, int j0, int j1, int j2,
                   float s0, float s1, float s2, int nt) {
      const int offs[3] = {0, 64, 256};
      const int ds[3]   = {1, 3, 9};
      Chunk c;
      c.wbase = p * 262144;
      c.o1[0] = offs[L1] + i0; c.o1[1] = offs[L1] + i1; c.o1[2] = offs[L1] + i2;
      c.o2[0] = offs[L2] + j0; c.o2[1] = offs[L2] + j1; c.o2[2] = offs[L2] + j2;
      c.sg[0] = s0; c.sg[1] = s1; c.sg[2] = s2;
      c.d1 = ds[L1]; c.d2 = ds[L2]; c.nt = nt;
      chs[n++] = c;
    };
    if (slot == 0) {
      add(0, 0,0, 0,0,0, 0,0,0, 1,0,0, 1);                  // A0*B0
      add(5, 1,1, 0,1,2, 0,1,2, 1,1,1, 3);                  // sum_e A1[e]B1[e]
      add(13,2,2, 0,1,2, 0,1,2, 1,1,1, 3);                  // sum_g A2[g]B2[g] (3 chunks)
      add(13,2,2, 3,4,5, 3,4,5, 1,1,1, 3);
      add(13,2,2, 6,7,8, 6,7,8, 1,1,1, 3);
    } else if (slot < 4) {
      const int m = slot - 1, p1 = (m+1)%3, p2 = (m+2)%3;
      add(1, 0,1, 0,0,0, m,0,0, 1,0,0, 1);                  // A0*B1[m]
      add(3, 1,0, m,0,0, 0,0,0, 1,0,0, 1);                  // A1[m]*B0
      add(6, 1,1, p1,p2,0, p2,p1,0, 1,-1,0, 2);             // eps(m,x,y)A1[x]B1[y]
      add(7, 1,2, 0,1,2, 3*m,3*m+1,3*m+2, 1,1,1, 3);        // sum_e A1[e]B2[m,e]
      add(10,2,1, 3*m,3*m+1,3*m+2, 0,1,2, 1,1,1, 3);        // sum_e A2[m,e]B1[e]
      add(14,2,2, 3*p1,3*p1+1,3*p1+2, 3*p2,3*p2+1,3*p2+2, 1,1,1, 3);    // +A2[p1,e]B2[p2,e]
      add(14,2,2, 3*p2,3*p2+1,3*p2+2, 3*p1,3*p1+1,3*p1+2, -1,-1,-1, 3); // -A2[p2,e]B2[p1,e]
    } else {
      const int m = slot - 4, u = m/3, v = m%3, q1 = (v+1)%3, q2 = (v+2)%3;
      add(2, 0,2, 0,0,0, m,0,0, 1,0,0, 1);                  // A0*B2[u,v]
      add(4, 1,1, u,0,0, v,0,0, 1,0,0, 1);                  // A1[u]*B1[v]
      add(8, 1,2, q1,q2,0, 3*u+q2,3*u+q1,0, 1,-1,0, 2);     // eps(v,x,y)A1[x]B2[u,y]
      add(9, 2,0, m,0,0, 0,0,0, 1,0,0, 1);                  // A2[u,v]*B0
      add(11,2,1, 3*u+q1,3*u+q2,0, q2,q1,0, 1,-1,0, 2);     // eps(v,e,f)A2[u,e]B1[f]
      add(12,2,2, 3*u,3*u+1,3*u+2, 3*v,3*v+1,3*v+2, 1,1,1, 3); // sum_e A2[u,e]B2[v,e]
    }
    nch_s = n;
  }
  __syncthreads();
  const int nch = nch_s;

  floatx16 acc0, acc1;
  #pragma unroll
  for (int r = 0; r < 16; ++r) { acc0[r] = 0.0f; acc1[r] = 0.0f; }

  for (int ci = half; ci < nch; ci += 2) {
    const Chunk C = chs[ci];  // block-uniform
    if (C.nt == 1)      run_chunk<1>(C, zbase, zl, hf, lane, tid, x1, x2, Wh, XS, acc0, acc1);
    else if (C.nt == 2) run_chunk<2>(C, zbase, zl, hf, lane, tid, x1, x2, Wh, XS, acc0, acc1);
    else                run_chunk<3>(C, zbase, zl, hf, lane, tid, x1, x2, Wh, XS, acc0, acc1);
  }

  // epilogue: C/D 32x32 layout: col(z)=lane&31, row(c)=(r&3)+8*(r>>2)+4*(lane>>5).
  // K-split partials combined with device-scope f32 atomics (out zero-initialized).
  float* __restrict__ op = out + (size_t)(zbase + zl) * FEAT + offO + mO;
  #pragma unroll
  for (int r = 0; r < 16; ++r) {
    const int cr = (r & 3) + 8 * (r >> 2) + 4 * hf;
    atomicAdd(op + (size_t)cr * dO,        acc0[r]);
    atomicAdd(op + (size_t)(cr + 32) * dO, acc1[r]);
  }
}

extern "C" void kernel_launch(void* const* d_in, const int* in_sizes, int n_in,
                              void* d_out, int out_size, void* d_ws, size_t ws_size,
                              hipStream_t stream) {
  const float* x1 = (const float*)d_in[0];
  const float* x2 = (const float*)d_in[1];
  const float* w  = (const float*)d_in[2];
  float* out = (float*)d_out;
  _Float16* Wh = (_Float16*)d_ws;            // 15*64*4096 f16 = 7.86 MB scratch (swizzled)

  const int nchunks = 15 * 64 * 4096 / 8;    // 491520 half8 chunks
  hipLaunchKernelGGL(swz_w_kernel, dim3(nchunks / 256), dim3(256), 0, stream, w, Wh);

  const int n4 = out_size / 4;               // 4096*832 floats -> float4 count
  hipLaunchKernelGGL(zero_out_kernel, dim3((n4 + 255) / 256), dim3(256), 0, stream,
                     (float4*)out, n4);

  dim3 grid(64, 13, 2);  // z-tiles x slots x K-split halves
  hipLaunchKernelGGL(tp_kernel, grid, dim3(128), 0, stream, x1, x2, Wh, out);
}

// Round 7
// 645.995 us; speedup vs baseline: 1.1955x; 1.1955x over previous
//
#include <hip/hip_runtime.h>
#include <cstdint>
#include <cstddef>

// PureCartesianTensorProduct: B=4096, C1=C2=COUT=64, LMAX=2, FEAT=832, 15 paths.
// out[z,c,m] = sum_p sum_ab W_p[c,a,b] * T_p,m[z,a,b].
// MFMA f32_32x32x16_f16. A = W pre-swizzled in A-frag order (global, L2-hot,
// 2-deep even/odd register prefetch). Wave = 1 z-group x 2 c-group accumulators
// sharing one tb. x2: coalesced LDS stage -> a-invariant regs (ds_read_b128).
// x1: f16 transposed LDS tile (stride 66 = 33 dwords, conflict-free), scalar
// per (a,z), prefetched. K-split x2 across blockIdx.z by chunk parity:
// half0 -> out, half1 -> ws partial buffer, then out += part (no atomics).

#define FEAT 832
#define ZT 64

typedef _Float16 half8 __attribute__((ext_vector_type(8)));
typedef float floatx16 __attribute__((ext_vector_type(16)));

struct Chunk {
  int wbase;      // p * 262144, element offset into swizzled f16 weight
  int o1[3];      // absolute x1 feature offset for term t (at a=0)
  int o2[3];      // absolute x2 feature offset for term t (at b=0)
  float sg[3];    // +-1
  int d1, d2, nt; // a-stride (3^L1), b-stride (3^L2), #terms (<=3)
};

// Swizzle W f32 [p][c][k] -> f16 A-frag order:
// Wsw[((p*256 + ksg)*2 + cgrp)*512 + lane*8 + j] = W_p[cgrp*32+(lane&31)][ksg*16+(lane>>5)*8+j]
__global__ void swz_w_kernel(const float* __restrict__ w, _Float16* __restrict__ o) {
  const int i = blockIdx.x * 256 + threadIdx.x;     // one half8 chunk per thread
  const int lane = i & 63;
  const int pkc  = i >> 6;
  const int cgrp = pkc & 1;
  const int ksg  = (pkc >> 1) & 255;
  const int p    = pkc >> 9;
  const int c  = cgrp * 32 + (lane & 31);
  const int k0 = ksg * 16 + (lane >> 5) * 8;
  const float* src = w + (size_t)p * 262144 + (size_t)c * 4096 + k0;
  const float4 v0 = *(const float4*)(src);
  const float4 v1 = *(const float4*)(src + 4);
  half8 h = { (_Float16)v0.x, (_Float16)v0.y, (_Float16)v0.z, (_Float16)v0.w,
              (_Float16)v1.x, (_Float16)v1.y, (_Float16)v1.z, (_Float16)v1.w };
  *(half8*)(o + (size_t)i * 8) = h;
}

__global__ void reduce_kernel(float4* __restrict__ o, const float4* __restrict__ p, int n4) {
  const int i = blockIdx.x * 256 + threadIdx.x;
  if (i < n4) {
    float4 a = o[i], b = p[i];
    o[i] = float4{a.x + b.x, a.y + b.y, a.z + b.z, a.w + b.w};
  }
}

__device__ __forceinline__ half8 splat8(_Float16 h) {
  return half8{h, h, h, h, h, h, h, h};
}

// XS union: X2 view [t][zz]*72+b; X1 view [t][a]*66+zz.
template<int NT>
__device__ __forceinline__ void run_chunk(
    const Chunk C, const int zbase, const int zl, const int hf,
    const int lane, const int tid,
    const float* __restrict__ x1, const float* __restrict__ x2,
    const _Float16* __restrict__ Wh, _Float16* __restrict__ XS,
    floatx16& acc0, floatx16& acc1)
{
  __syncthreads();  // previous chunk's X1-view readers done

  // stage x2 tile coalesced: XS[(t*64+zz)*72+b] = (f16) x2[zbase+zz, o2[t]+b*d2]
  #pragma unroll
  for (int t = 0; t < NT; ++t) {
    const size_t base2 = (size_t)zbase * FEAT + C.o2[t];
    for (int e = tid; e < 4096; e += 128) {
      const int zz = e >> 6, b = e & 63;
      XS[(t * 64 + zz) * 72 + b] =
          (_Float16)x2[base2 + (size_t)zz * FEAT + b * C.d2];
    }
  }
  __syncthreads();

  // a-invariant x2 register fragments (ds_read_b128)
  half8 x2r[NT][4];
  #pragma unroll
  for (int t = 0; t < NT; ++t) {
    #pragma unroll
    for (int ks = 0; ks < 4; ++ks)
      x2r[t][ks] = *(const half8*)&XS[(t * 64 + zl) * 72 + ks * 16 + hf * 8];
  }
  __syncthreads();  // all x2-view reads done before X1 writes

  // stage x1 transposed [t][a][z] stride 66, sign folded
  #pragma unroll
  for (int t = 0; t < NT; ++t) {
    const float sgf = C.sg[t];
    const int o1 = C.o1[t];
    for (int e = tid; e < 4096; e += 128) {
      const int a = e & 63, zz = e >> 6;
      XS[(t * 64 + a) * 66 + zz] =
          (_Float16)(x1[(size_t)(zbase + zz) * FEAT + o1 + a * C.d1] * sgf);
    }
  }
  __syncthreads();

  const _Float16* __restrict__ Wq = Wh + C.wbase + lane * 8;
  const _Float16* __restrict__ Xq = XS + zl;

  // 2-deep W prefetch: even/odd a buffers, [cgrp][ks]
  half8 afE[2][4], afO[2][4];
  #pragma unroll
  for (int ks = 0; ks < 4; ++ks) {
    afE[0][ks] = *(const half8*)(Wq + ks * 1024);
    afE[1][ks] = *(const half8*)(Wq + ks * 1024 + 512);
    afO[0][ks] = *(const half8*)(Wq + 4096 + ks * 1024);
    afO[1][ks] = *(const half8*)(Wq + 4096 + ks * 1024 + 512);
  }
  _Float16 sc[NT], scn[NT];
  #pragma unroll
  for (int t = 0; t < NT; ++t) {
    sc[t]  = Xq[(t * 64 + 0) * 66];
    scn[t] = Xq[(t * 64 + 1) * 66];
  }

  #pragma unroll 1
  for (int a = 0; a < 64; a += 2) {
    {  // even: compute a, prefetch a+2
      half8 sv[NT];
      #pragma unroll
      for (int t = 0; t < NT; ++t) sv[t] = splat8(sc[t]);
      if (a + 2 < 64) {
        #pragma unroll
        for (int t = 0; t < NT; ++t) sc[t] = Xq[(t * 64 + a + 2) * 66];
      }
      #pragma unroll
      for (int ks = 0; ks < 4; ++ks) {
        half8 tb = sv[0] * x2r[0][ks];
        if (NT > 1) tb += sv[1] * x2r[1][ks];
        if (NT > 2) tb += sv[2] * x2r[2][ks];
        acc0 = __builtin_amdgcn_mfma_f32_32x32x16_f16(afE[0][ks], tb, acc0, 0, 0, 0);
        acc1 = __builtin_amdgcn_mfma_f32_32x32x16_f16(afE[1][ks], tb, acc1, 0, 0, 0);
      }
      if (a + 2 < 64) {
        const _Float16* wn = Wq + (a + 2) * 4096;
        #pragma unroll
        for (int ks = 0; ks < 4; ++ks) {
          afE[0][ks] = *(const half8*)(wn + ks * 1024);
          afE[1][ks] = *(const half8*)(wn + ks * 1024 + 512);
        }
      }
    }
    {  // odd: compute a+1, prefetch a+3
      half8 sv[NT];
      #pragma unroll
      for (int t = 0; t < NT; ++t) sv[t] = splat8(scn[t]);
      if (a + 3 < 64) {
        #pragma unroll
        for (int t = 0; t < NT; ++t) scn[t] = Xq[(t * 64 + a + 3) * 66];
      }
      #pragma unroll
      for (int ks = 0; ks < 4; ++ks) {
        half8 tb = sv[0] * x2r[0][ks];
        if (NT > 1) tb += sv[1] * x2r[1][ks];
        if (NT > 2) tb += sv[2] * x2r[2][ks];
        acc0 = __builtin_amdgcn_mfma_f32_32x32x16_f16(afO[0][ks], tb, acc0, 0, 0, 0);
        acc1 = __builtin_amdgcn_mfma_f32_32x32x16_f16(afO[1][ks], tb, acc1, 0, 0, 0);
      }
      if (a + 3 < 64) {
        const _Float16* wn = Wq + (a + 3) * 4096;
        #pragma unroll
        for (int ks = 0; ks < 4; ++ks) {
          afO[0][ks] = *(const half8*)(wn + ks * 1024);
          afO[1][ks] = *(const half8*)(wn + ks * 1024 + 512);
        }
      }
    }
  }
}

__global__ __launch_bounds__(128, 3) void tp_kernel(
    const float* __restrict__ x1, const float* __restrict__ x2,
    const _Float16* __restrict__ Wh, float* __restrict__ out,
    float* __restrict__ part)
{
  __shared__ __align__(16) _Float16 XS[3 * 64 * 72]; // 27648 B union (X2/X1 views)
  __shared__ Chunk chs[7];
  __shared__ int nch_s;

  const int tid  = threadIdx.x;
  const int slot = blockIdx.y;           // 0: L0; 1..3: L1 m; 4..12: L2 (u,v)
  const int half = blockIdx.z;           // K-split: chunk parity
  const int zbase = blockIdx.x * ZT;
  const int zgrp = tid >> 6;             // wave = z-group
  const int lane = tid & 63;
  const int ln31 = lane & 31;
  const int hf   = lane >> 5;
  const int zl   = zgrp * 32 + ln31;     // B-frag col z within tile

  int offO, dO, mO;
  if (slot == 0)      { offO = 0;   dO = 1; mO = 0; }
  else if (slot < 4)  { offO = 64;  dO = 3; mO = slot - 1; }
  else                { offO = 256; dO = 9; mO = slot - 4; }

  if (tid == 0) {
    int n = 0;
    auto add = [&](int p, int L1, int L2,
                   int i0, int i1, int i2, int j0, int j1, int j2,
                   float s0, float s1, float s2, int nt) {
      const int offs[3] = {0, 64, 256};
      const int ds[3]   = {1, 3, 9};
      Chunk c;
      c.wbase = p * 262144;
      c.o1[0] = offs[L1] + i0; c.o1[1] = offs[L1] + i1; c.o1[2] = offs[L1] + i2;
      c.o2[0] = offs[L2] + j0; c.o2[1] = offs[L2] + j1; c.o2[2] = offs[L2] + j2;
      c.sg[0] = s0; c.sg[1] = s1; c.sg[2] = s2;
      c.d1 = ds[L1]; c.d2 = ds[L2]; c.nt = nt;
      chs[n++] = c;
    };
    if (slot == 0) {
      add(0, 0,0, 0,0,0, 0,0,0, 1,0,0, 1);                  // A0*B0
      add(5, 1,1, 0,1,2, 0,1,2, 1,1,1, 3);                  // sum_e A1[e]B1[e]
      add(13,2,2, 0,1,2, 0,1,2, 1,1,1, 3);                  // sum_g A2[g]B2[g] (3 chunks)
      add(13,2,2, 3,4,5, 3,4,5, 1,1,1, 3);
      add(13,2,2, 6,7,8, 6,7,8, 1,1,1, 3);
    } else if (slot < 4) {
      const int m = slot - 1, p1 = (m+1)%3, p2 = (m+2)%3;
      add(1, 0,1, 0,0,0, m,0,0, 1,0,0, 1);                  // A0*B1[m]
      add(3, 1,0, m,0,0, 0,0,0, 1,0,0, 1);                  // A1[m]*B0
      add(6, 1,1, p1,p2,0, p2,p1,0, 1,-1,0, 2);             // eps(m,x,y)A1[x]B1[y]
      add(7, 1,2, 0,1,2, 3*m,3*m+1,3*m+2, 1,1,1, 3);        // sum_e A1[e]B2[m,e]
      add(10,2,1, 3*m,3*m+1,3*m+2, 0,1,2, 1,1,1, 3);        // sum_e A2[m,e]B1[e]
      add(14,2,2, 3*p1,3*p1+1,3*p1+2, 3*p2,3*p2+1,3*p2+2, 1,1,1, 3);    // +A2[p1,e]B2[p2,e]
      add(14,2,2, 3*p2,3*p2+1,3*p2+2, 3*p1,3*p1+1,3*p1+2, -1,-1,-1, 3); // -A2[p2,e]B2[p1,e]
    } else {
      const int m = slot - 4, u = m/3, v = m%3, q1 = (v+1)%3, q2 = (v+2)%3;
      add(2, 0,2, 0,0,0, m,0,0, 1,0,0, 1);                  // A0*B2[u,v]
      add(4, 1,1, u,0,0, v,0,0, 1,0,0, 1);                  // A1[u]*B1[v]
      add(8, 1,2, q1,q2,0, 3*u+q2,3*u+q1,0, 1,-1,0, 2);     // eps(v,x,y)A1[x]B2[u,y]
      add(9, 2,0, m,0,0, 0,0,0, 1,0,0, 1);                  // A2[u,v]*B0
      add(11,2,1, 3*u+q1,3*u+q2,0, q2,q1,0, 1,-1,0, 2);     // eps(v,e,f)A2[u,e]B1[f]
      add(12,2,2, 3*u,3*u+1,3*u+2, 3*v,3*v+1,3*v+2, 1,1,1, 3); // sum_e A2[u,e]B2[v,e]
    }
    nch_s = n;
  }
  __syncthreads();
  const int nch = nch_s;

  floatx16 acc0, acc1;
  #pragma unroll
  for (int r = 0; r < 16; ++r) { acc0[r] = 0.0f; acc1[r] = 0.0f; }

  for (int ci = half; ci < nch; ci += 2) {
    const Chunk C = chs[ci];  // block-uniform
    if (C.nt == 1)      run_chunk<1>(C, zbase, zl, hf, lane, tid, x1, x2, Wh, XS, acc0, acc1);
    else if (C.nt == 2) run_chunk<2>(C, zbase, zl, hf, lane, tid, x1, x2, Wh, XS, acc0, acc1);
    else                run_chunk<3>(C, zbase, zl, hf, lane, tid, x1, x2, Wh, XS, acc0, acc1);
  }

  // epilogue: C/D 32x32 layout: col(z)=lane&31, row(c)=(r&3)+8*(r>>2)+4*(lane>>5).
  // half0 -> out, half1 -> part; disjoint writes, combined by reduce_kernel.
  float* __restrict__ dst = (half == 0) ? out : part;
  float* __restrict__ op = dst + (size_t)(zbase + zl) * FEAT + offO + mO;
  #pragma unroll
  for (int r = 0; r < 16; ++r) {
    const int cr = (r & 3) + 8 * (r >> 2) + 4 * hf;
    op[(size_t)cr * dO]        = acc0[r];
    op[(size_t)(cr + 32) * dO] = acc1[r];
  }
}

extern "C" void kernel_launch(void* const* d_in, const int* in_sizes, int n_in,
                              void* d_out, int out_size, void* d_ws, size_t ws_size,
                              hipStream_t stream) {
  const float* x1 = (const float*)d_in[0];
  const float* x2 = (const float*)d_in[1];
  const float* w  = (const float*)d_in[2];
  float* out = (float*)d_out;
  _Float16* Wh = (_Float16*)d_ws;            // 15*64*4096 f16 = 7,864,320 B (swizzled)
  float* part = (float*)((char*)d_ws + 7864320);  // 4096*832 f32 = 13.6 MB partials

  const int nchunks = 15 * 64 * 4096 / 8;    // 491520 half8 chunks
  hipLaunchKernelGGL(swz_w_kernel, dim3(nchunks / 256), dim3(256), 0, stream, w, Wh);

  dim3 grid(64, 13, 2);  // z-tiles x slots x K-split halves
  hipLaunchKernelGGL(tp_kernel, grid, dim3(128), 0, stream, x1, x2, Wh, out, part);

  const int n4 = out_size / 4;               // float4 count
  hipLaunchKernelGGL(reduce_kernel, dim3((n4 + 255) / 256), dim3(256), 0, stream,
                     (float4*)out, (const float4*)part, n4);
}

// Round 8
// 381.234 us; speedup vs baseline: 2.0257x; 1.6945x over previous
//
#include <hip/hip_runtime.h>
#include <cstdint>
#include <cstddef>

// PureCartesianTensorProduct: B=4096, C1=C2=COUT=64, LMAX=2, FEAT=832, 15 paths.
// out[z,c,m] = sum_p sum_ab W_p[c,a,b] * T_p,m[z,a,b].
// MFMA f32_32x32x16_f16. A = W pre-swizzled in A-frag order (global, L2-hot,
// 2-deep even/odd register prefetch). Wave = 1 z-group x 2 c-group accumulators
// sharing one tb. x2: coalesced LDS stage -> a-invariant regs (ds_read_b128).
// x1: f16 transposed LDS tile (stride 66 = 33 dwords, conflict-free).
// K-split x2 by chunk parity: half0 -> out (direct), half1 -> slot-major
// transposed planes part[slot][c][z] (full-line coalesced stores), then a
// LDS-transpose gather kernel does out += part. No atomics anywhere.

#define FEAT 832
#define ZT 64

typedef _Float16 half8 __attribute__((ext_vector_type(8)));
typedef float floatx16 __attribute__((ext_vector_type(16)));

struct Chunk {
  int wbase;      // p * 262144, element offset into swizzled f16 weight
  int o1[3];      // absolute x1 feature offset for term t (at a=0)
  int o2[3];      // absolute x2 feature offset for term t (at b=0)
  float sg[3];    // +-1
  int d1, d2, nt; // a-stride (3^L1), b-stride (3^L2), #terms (<=3)
};

// Swizzle W f32 [p][c][k] -> f16 A-frag order:
// Wsw[((p*256 + ksg)*2 + cgrp)*512 + lane*8 + j] = W_p[cgrp*32+(lane&31)][ksg*16+(lane>>5)*8+j]
__global__ void swz_w_kernel(const float* __restrict__ w, _Float16* __restrict__ o) {
  const int i = blockIdx.x * 256 + threadIdx.x;     // one half8 chunk per thread
  const int lane = i & 63;
  const int pkc  = i >> 6;
  const int cgrp = pkc & 1;
  const int ksg  = (pkc >> 1) & 255;
  const int p    = pkc >> 9;
  const int c  = cgrp * 32 + (lane & 31);
  const int k0 = ksg * 16 + (lane >> 5) * 8;
  const float* src = w + (size_t)p * 262144 + (size_t)c * 4096 + k0;
  const float4 v0 = *(const float4*)(src);
  const float4 v1 = *(const float4*)(src + 4);
  half8 h = { (_Float16)v0.x, (_Float16)v0.y, (_Float16)v0.z, (_Float16)v0.w,
              (_Float16)v1.x, (_Float16)v1.y, (_Float16)v1.z, (_Float16)v1.w };
  *(half8*)(o + (size_t)i * 8) = h;
}

// out[z][f] += part[s(f)][c(f)][z], via 64x64 LDS transpose tile.
// All global reads/writes coalesced; LDS strides conflict-free.
__global__ __launch_bounds__(256) void gather_kernel(
    float* __restrict__ out, const float* __restrict__ part)
{
  __shared__ float T[64][65];
  const int zb = blockIdx.x * 64;   // 64 z-tiles
  const int fb = blockIdx.y * 64;   // 13 f-tiles
  const int tid = threadIdx.x;
  const int fl = tid >> 6;          // 0..3
  const int zl = tid & 63;
  #pragma unroll
  for (int i = 0; i < 16; ++i) {
    const int f = fb + fl + i * 4;
    int s, c;
    if (f < 64)       { s = 0;              c = f; }
    else if (f < 256) { const int g = f - 64;  c = g / 3; s = 1 + g % 3; }
    else              { const int g = f - 256; c = g / 9; s = 4 + g % 9; }
    T[fl + i * 4][zl] = part[(size_t)s * 262144 + (size_t)c * 4096 + zb + zl];
  }
  __syncthreads();
  const int zr = tid >> 6;          // 0..3
  const int fc = tid & 63;
  #pragma unroll
  for (int i = 0; i < 16; ++i) {
    const int z = zr + i * 4;
    float* o = out + (size_t)(zb + z) * FEAT + fb + fc;
    *o += T[fc][z];
  }
}

__device__ __forceinline__ half8 splat8(_Float16 h) {
  return half8{h, h, h, h, h, h, h, h};
}

// XS union: X2 view [t][zz]*72+b; X1 view [t][a]*66+zz.
template<int NT>
__device__ __forceinline__ void run_chunk(
    const Chunk C, const int zbase, const int zl, const int hf,
    const int lane, const int tid,
    const float* __restrict__ x1, const float* __restrict__ x2,
    const _Float16* __restrict__ Wh, _Float16* __restrict__ XS,
    floatx16& acc0, floatx16& acc1)
{
  __syncthreads();  // previous chunk's X1-view readers done

  // stage x2 tile coalesced: XS[(t*64+zz)*72+b] = (f16) x2[zbase+zz, o2[t]+b*d2]
  #pragma unroll
  for (int t = 0; t < NT; ++t) {
    const size_t base2 = (size_t)zbase * FEAT + C.o2[t];
    for (int e = tid; e < 4096; e += 128) {
      const int zz = e >> 6, b = e & 63;
      XS[(t * 64 + zz) * 72 + b] =
          (_Float16)x2[base2 + (size_t)zz * FEAT + b * C.d2];
    }
  }
  __syncthreads();

  // a-invariant x2 register fragments (ds_read_b128)
  half8 x2r[NT][4];
  #pragma unroll
  for (int t = 0; t < NT; ++t) {
    #pragma unroll
    for (int ks = 0; ks < 4; ++ks)
      x2r[t][ks] = *(const half8*)&XS[(t * 64 + zl) * 72 + ks * 16 + hf * 8];
  }
  __syncthreads();  // all x2-view reads done before X1 writes

  // stage x1 transposed [t][a][z] stride 66, sign folded
  #pragma unroll
  for (int t = 0; t < NT; ++t) {
    const float sgf = C.sg[t];
    const int o1 = C.o1[t];
    for (int e = tid; e < 4096; e += 128) {
      const int a = e & 63, zz = e >> 6;
      XS[(t * 64 + a) * 66 + zz] =
          (_Float16)(x1[(size_t)(zbase + zz) * FEAT + o1 + a * C.d1] * sgf);
    }
  }
  __syncthreads();

  const _Float16* __restrict__ Wq = Wh + C.wbase + lane * 8;
  const _Float16* __restrict__ Xq = XS + zl;

  // 2-deep W prefetch: even/odd a buffers, [cgrp][ks]
  half8 afE[2][4], afO[2][4];
  #pragma unroll
  for (int ks = 0; ks < 4; ++ks) {
    afE[0][ks] = *(const half8*)(Wq + ks * 1024);
    afE[1][ks] = *(const half8*)(Wq + ks * 1024 + 512);
    afO[0][ks] = *(const half8*)(Wq + 4096 + ks * 1024);
    afO[1][ks] = *(const half8*)(Wq + 4096 + ks * 1024 + 512);
  }
  _Float16 sc[NT], scn[NT];
  #pragma unroll
  for (int t = 0; t < NT; ++t) {
    sc[t]  = Xq[(t * 64 + 0) * 66];
    scn[t] = Xq[(t * 64 + 1) * 66];
  }

  #pragma unroll 1
  for (int a = 0; a < 64; a += 2) {
    {  // even: compute a, prefetch a+2
      half8 sv[NT];
      #pragma unroll
      for (int t = 0; t < NT; ++t) sv[t] = splat8(sc[t]);
      if (a + 2 < 64) {
        #pragma unroll
        for (int t = 0; t < NT; ++t) sc[t] = Xq[(t * 64 + a + 2) * 66];
      }
      #pragma unroll
      for (int ks = 0; ks < 4; ++ks) {
        half8 tb = sv[0] * x2r[0][ks];
        if (NT > 1) tb += sv[1] * x2r[1][ks];
        if (NT > 2) tb += sv[2] * x2r[2][ks];
        acc0 = __builtin_amdgcn_mfma_f32_32x32x16_f16(afE[0][ks], tb, acc0, 0, 0, 0);
        acc1 = __builtin_amdgcn_mfma_f32_32x32x16_f16(afE[1][ks], tb, acc1, 0, 0, 0);
      }
      if (a + 2 < 64) {
        const _Float16* wn = Wq + (a + 2) * 4096;
        #pragma unroll
        for (int ks = 0; ks < 4; ++ks) {
          afE[0][ks] = *(const half8*)(wn + ks * 1024);
          afE[1][ks] = *(const half8*)(wn + ks * 1024 + 512);
        }
      }
    }
    {  // odd: compute a+1, prefetch a+3
      half8 sv[NT];
      #pragma unroll
      for (int t = 0; t < NT; ++t) sv[t] = splat8(scn[t]);
      if (a + 3 < 64) {
        #pragma unroll
        for (int t = 0; t < NT; ++t) scn[t] = Xq[(t * 64 + a + 3) * 66];
      }
      #pragma unroll
      for (int ks = 0; ks < 4; ++ks) {
        half8 tb = sv[0] * x2r[0][ks];
        if (NT > 1) tb += sv[1] * x2r[1][ks];
        if (NT > 2) tb += sv[2] * x2r[2][ks];
        acc0 = __builtin_amdgcn_mfma_f32_32x32x16_f16(afO[0][ks], tb, acc0, 0, 0, 0);
        acc1 = __builtin_amdgcn_mfma_f32_32x32x16_f16(afO[1][ks], tb, acc1, 0, 0, 0);
      }
      if (a + 3 < 64) {
        const _Float16* wn = Wq + (a + 3) * 4096;
        #pragma unroll
        for (int ks = 0; ks < 4; ++ks) {
          afO[0][ks] = *(const half8*)(wn + ks * 1024);
          afO[1][ks] = *(const half8*)(wn + ks * 1024 + 512);
        }
      }
    }
  }
}

__global__ __launch_bounds__(128, 2) void tp_kernel(
    const float* __restrict__ x1, const float* __restrict__ x2,
    const _Float16* __restrict__ Wh, float* __restrict__ out,
    float* __restrict__ part)
{
  __shared__ __align__(16) _Float16 XS[3 * 64 * 72]; // 27648 B union (X2/X1 views)
  __shared__ Chunk chs[7];
  __shared__ int nch_s;

  const int tid  = threadIdx.x;
  const int slot = blockIdx.y;           // 0: L0; 1..3: L1 m; 4..12: L2 (u,v)
  const int half = blockIdx.z;           // K-split: chunk parity
  const int zbase = blockIdx.x * ZT;
  const int zgrp = tid >> 6;             // wave = z-group
  const int lane = tid & 63;
  const int ln31 = lane & 31;
  const int hf   = lane >> 5;
  const int zl   = zgrp * 32 + ln31;     // B-frag col z within tile

  int offO, dO, mO;
  if (slot == 0)      { offO = 0;   dO = 1; mO = 0; }
  else if (slot < 4)  { offO = 64;  dO = 3; mO = slot - 1; }
  else                { offO = 256; dO = 9; mO = slot - 4; }

  if (tid == 0) {
    int n = 0;
    auto add = [&](int p, int L1, int L2,
                   int i0, int i1, int i2, int j0, int j1, int j2,
                   float s0, float s1, float s2, int nt) {
      const int offs[3] = {0, 64, 256};
      const int ds[3]   = {1, 3, 9};
      Chunk c;
      c.wbase = p * 262144;
      c.o1[0] = offs[L1] + i0; c.o1[1] = offs[L1] + i1; c.o1[2] = offs[L1] + i2;
      c.o2[0] = offs[L2] + j0; c.o2[1] = offs[L2] + j1; c.o2[2] = offs[L2] + j2;
      c.sg[0] = s0; c.sg[1] = s1; c.sg[2] = s2;
      c.d1 = ds[L1]; c.d2 = ds[L2]; c.nt = nt;
      chs[n++] = c;
    };
    if (slot == 0) {
      add(0, 0,0, 0,0,0, 0,0,0, 1,0,0, 1);                  // A0*B0
      add(5, 1,1, 0,1,2, 0,1,2, 1,1,1, 3);                  // sum_e A1[e]B1[e]
      add(13,2,2, 0,1,2, 0,1,2, 1,1,1, 3);                  // sum_g A2[g]B2[g] (3 chunks)
      add(13,2,2, 3,4,5, 3,4,5, 1,1,1, 3);
      add(13,2,2, 6,7,8, 6,7,8, 1,1,1, 3);
    } else if (slot < 4) {
      const int m = slot - 1, p1 = (m+1)%3, p2 = (m+2)%3;
      add(1, 0,1, 0,0,0, m,0,0, 1,0,0, 1);                  // A0*B1[m]
      add(3, 1,0, m,0,0, 0,0,0, 1,0,0, 1);                  // A1[m]*B0
      add(6, 1,1, p1,p2,0, p2,p1,0, 1,-1,0, 2);             // eps(m,x,y)A1[x]B1[y]
      add(7, 1,2, 0,1,2, 3*m,3*m+1,3*m+2, 1,1,1, 3);        // sum_e A1[e]B2[m,e]
      add(10,2,1, 3*m,3*m+1,3*m+2, 0,1,2, 1,1,1, 3);        // sum_e A2[m,e]B1[e]
      add(14,2,2, 3*p1,3*p1+1,3*p1+2, 3*p2,3*p2+1,3*p2+2, 1,1,1, 3);    // +A2[p1,e]B2[p2,e]
      add(14,2,2, 3*p2,3*p2+1,3*p2+2, 3*p1,3*p1+1,3*p1+2, -1,-1,-1, 3); // -A2[p2,e]B2[p1,e]
    } else {
      const int m = slot - 4, u = m/3, v = m%3, q1 = (v+1)%3, q2 = (v+2)%3;
      add(2, 0,2, 0,0,0, m,0,0, 1,0,0, 1);                  // A0*B2[u,v]
      add(4, 1,1, u,0,0, v,0,0, 1,0,0, 1);                  // A1[u]*B1[v]
      add(8, 1,2, q1,q2,0, 3*u+q2,3*u+q1,0, 1,-1,0, 2);     // eps(v,x,y)A1[x]B2[u,y]
      add(9, 2,0, m,0,0, 0,0,0, 1,0,0, 1);                  // A2[u,v]*B0
      add(11,2,1, 3*u+q1,3*u+q2,0, q2,q1,0, 1,-1,0, 2);     // eps(v,e,f)A2[u,e]B1[f]
      add(12,2,2, 3*u,3*u+1,3*u+2, 3*v,3*v+1,3*v+2, 1,1,1, 3); // sum_e A2[u,e]B2[v,e]
    }
    nch_s = n;
  }
  __syncthreads();
  const int nch = nch_s;

  floatx16 acc0, acc1;
  #pragma unroll
  for (int r = 0; r < 16; ++r) { acc0[r] = 0.0f; acc1[r] = 0.0f; }

  for (int ci = half; ci < nch; ci += 2) {
    const Chunk C = chs[ci];  // block-uniform
    if (C.nt == 1)      run_chunk<1>(C, zbase, zl, hf, lane, tid, x1, x2, Wh, XS, acc0, acc1);
    else if (C.nt == 2) run_chunk<2>(C, zbase, zl, hf, lane, tid, x1, x2, Wh, XS, acc0, acc1);
    else                run_chunk<3>(C, zbase, zl, hf, lane, tid, x1, x2, Wh, XS, acc0, acc1);
  }

  // epilogue: C/D 32x32 layout: col(z)=lane&31, row(c)=(r&3)+8*(r>>2)+4*(lane>>5).
  if (half == 0) {
    // direct interleaved store to out
    float* __restrict__ op = out + (size_t)(zbase + zl) * FEAT + offO + mO;
    #pragma unroll
    for (int r = 0; r < 16; ++r) {
      const int cr = (r & 3) + 8 * (r >> 2) + 4 * hf;
      op[(size_t)cr * dO]        = acc0[r];
      op[(size_t)(cr + 32) * dO] = acc1[r];
    }
  } else {
    // slot-major transposed plane: part[slot][c][z] -> lanes contiguous in z
    float* __restrict__ op = part + (size_t)slot * 262144 + (zbase + zl);
    #pragma unroll
    for (int r = 0; r < 16; ++r) {
      const int cr = (r & 3) + 8 * (r >> 2) + 4 * hf;
      op[(size_t)cr * 4096]        = acc0[r];
      op[(size_t)(cr + 32) * 4096] = acc1[r];
    }
  }
}

extern "C" void kernel_launch(void* const* d_in, const int* in_sizes, int n_in,
                              void* d_out, int out_size, void* d_ws, size_t ws_size,
                              hipStream_t stream) {
  const float* x1 = (const float*)d_in[0];
  const float* x2 = (const float*)d_in[1];
  const float* w  = (const float*)d_in[2];
  float* out = (float*)d_out;
  _Float16* Wh = (_Float16*)d_ws;            // 15*64*4096 f16 = 7,864,320 B (swizzled)
  float* part = (float*)((char*)d_ws + 7864320);  // 13 planes x 64c x 4096z f32 = 13.6 MB

  const int nchunks = 15 * 64 * 4096 / 8;    // 491520 half8 chunks
  hipLaunchKernelGGL(swz_w_kernel, dim3(nchunks / 256), dim3(256), 0, stream, w, Wh);

  dim3 grid(64, 13, 2);  // z-tiles x slots x K-split halves
  hipLaunchKernelGGL(tp_kernel, grid, dim3(128), 0, stream, x1, x2, Wh, out, part);

  dim3 ggrid(64, 13);    // z-tiles x f-tiles
  hipLaunchKernelGGL(gather_kernel, ggrid, dim3(256), 0, stream, out, part);
}

// Round 9
// 377.084 us; speedup vs baseline: 2.0480x; 1.0110x over previous
//
#include <hip/hip_runtime.h>
#include <cstdint>
#include <cstddef>

// PureCartesianTensorProduct: B=4096, C1=C2=COUT=64, LMAX=2, FEAT=832, 15 paths.
// out[z,c,m] = sum_p sum_ab W_p[c,a,b] * T_p,m[z,a,b].
// MFMA f32_32x32x16_f16. A = W pre-swizzled in A-frag order (global, L2-hot,
// 2-deep even/odd register prefetch). Wave = 1 z-group x 2 c-group accumulators
// sharing one tb. x2 + x1 staged to SEPARATE LDS buffers in one barrier window
// (53.2 KB total = 3 blocks/CU, same as the 148-reg unified-file cap).
// K-split x(np+1) by chunk index mod nsplit: quarter 0 -> out direct, quarters
// q>0 -> slot-major f32 planes part[q-1][slot][c][z] (full-line coalesced),
// then an LDS-transpose gather kernel does out += sum(planes). No atomics.

#define FEAT 832
#define ZT 64

typedef _Float16 half8 __attribute__((ext_vector_type(8)));
typedef float floatx16 __attribute__((ext_vector_type(16)));

struct Chunk {
  int wbase;      // p * 262144, element offset into swizzled f16 weight
  int o1[3];      // absolute x1 feature offset for term t (at a=0)
  int o2[3];      // absolute x2 feature offset for term t (at b=0)
  float sg[3];    // +-1
  int d1, d2, nt; // a-stride (3^L1), b-stride (3^L2), #terms (<=3)
};

// Swizzle W f32 [p][c][k] -> f16 A-frag order:
// Wsw[((p*256 + ksg)*2 + cgrp)*512 + lane*8 + j] = W_p[cgrp*32+(lane&31)][ksg*16+(lane>>5)*8+j]
__global__ void swz_w_kernel(const float* __restrict__ w, _Float16* __restrict__ o) {
  const int i = blockIdx.x * 256 + threadIdx.x;     // one half8 chunk per thread
  const int lane = i & 63;
  const int pkc  = i >> 6;
  const int cgrp = pkc & 1;
  const int ksg  = (pkc >> 1) & 255;
  const int p    = pkc >> 9;
  const int c  = cgrp * 32 + (lane & 31);
  const int k0 = ksg * 16 + (lane >> 5) * 8;
  const float* src = w + (size_t)p * 262144 + (size_t)c * 4096 + k0;
  const float4 v0 = *(const float4*)(src);
  const float4 v1 = *(const float4*)(src + 4);
  half8 h = { (_Float16)v0.x, (_Float16)v0.y, (_Float16)v0.z, (_Float16)v0.w,
              (_Float16)v1.x, (_Float16)v1.y, (_Float16)v1.z, (_Float16)v1.w };
  *(half8*)(o + (size_t)i * 8) = h;
}

// out[z][f] += sum_q part[q][s(f)][c(f)][z], via 64x64 LDS transpose tile.
__global__ __launch_bounds__(256) void gather_kernel(
    float* __restrict__ out, const float* __restrict__ part, int np)
{
  __shared__ float T[64][65];
  const int zb = blockIdx.x * 64;   // 64 z-tiles
  const int fb = blockIdx.y * 64;   // 13 f-tiles
  const int tid = threadIdx.x;
  const int fl = tid >> 6;          // 0..3
  const int zl = tid & 63;
  #pragma unroll
  for (int i = 0; i < 16; ++i) {
    const int f = fb + fl + i * 4;
    int s, c;
    if (f < 64)       { s = 0;              c = f; }
    else if (f < 256) { const int g = f - 64;  c = g / 3; s = 1 + g % 3; }
    else              { const int g = f - 256; c = g / 9; s = 4 + g % 9; }
    const size_t base = (size_t)s * 262144 + (size_t)c * 4096 + zb + zl;
    float v = 0.0f;
    for (int q = 0; q < np; ++q)
      v += part[(size_t)q * 3407872 + base];
    T[fl + i * 4][zl] = v;
  }
  __syncthreads();
  const int zr = tid >> 6;          // 0..3
  const int fc = tid & 63;
  #pragma unroll
  for (int i = 0; i < 16; ++i) {
    const int z = zr + i * 4;
    float* o = out + (size_t)(zb + z) * FEAT + fb + fc;
    *o += T[fc][z];
  }
}

__device__ __forceinline__ half8 splat8(_Float16 h) {
  return half8{h, h, h, h, h, h, h, h};
}

// XS2: [t][zz]*72+b (27648 B). XS1: [t][a]*66+zz (25344 B). Separate buffers.
template<int NT>
__device__ __forceinline__ void run_chunk(
    const Chunk C, const int zbase, const int zl, const int hf,
    const int lane, const int tid,
    const float* __restrict__ x1, const float* __restrict__ x2,
    const _Float16* __restrict__ Wh,
    _Float16* __restrict__ XS2, _Float16* __restrict__ XS1,
    floatx16& acc0, floatx16& acc1)
{
  __syncthreads();  // previous chunk's LDS readers done

  // stage x2 and x1 in ONE barrier window (disjoint buffers, no hazard)
  #pragma unroll
  for (int t = 0; t < NT; ++t) {
    const size_t base2 = (size_t)zbase * FEAT + C.o2[t];
    for (int e = tid; e < 4096; e += 128) {
      const int zz = e >> 6, b = e & 63;
      XS2[(t * 64 + zz) * 72 + b] =
          (_Float16)x2[base2 + (size_t)zz * FEAT + b * C.d2];
    }
  }
  #pragma unroll
  for (int t = 0; t < NT; ++t) {
    const float sgf = C.sg[t];
    const int o1 = C.o1[t];
    for (int e = tid; e < 4096; e += 128) {
      const int a = e & 63, zz = e >> 6;
      XS1[(t * 64 + a) * 66 + zz] =
          (_Float16)(x1[(size_t)(zbase + zz) * FEAT + o1 + a * C.d1] * sgf);
    }
  }
  __syncthreads();

  // a-invariant x2 register fragments (ds_read_b128)
  half8 x2r[NT][4];
  #pragma unroll
  for (int t = 0; t < NT; ++t) {
    #pragma unroll
    for (int ks = 0; ks < 4; ++ks)
      x2r[t][ks] = *(const half8*)&XS2[(t * 64 + zl) * 72 + ks * 16 + hf * 8];
  }

  const _Float16* __restrict__ Wq = Wh + C.wbase + lane * 8;
  const _Float16* __restrict__ Xq = XS1 + zl;

  // 2-deep W prefetch: even/odd a buffers, [cgrp][ks]
  half8 afE[2][4], afO[2][4];
  #pragma unroll
  for (int ks = 0; ks < 4; ++ks) {
    afE[0][ks] = *(const half8*)(Wq + ks * 1024);
    afE[1][ks] = *(const half8*)(Wq + ks * 1024 + 512);
    afO[0][ks] = *(const half8*)(Wq + 4096 + ks * 1024);
    afO[1][ks] = *(const half8*)(Wq + 4096 + ks * 1024 + 512);
  }
  _Float16 sc[NT], scn[NT];
  #pragma unroll
  for (int t = 0; t < NT; ++t) {
    sc[t]  = Xq[(t * 64 + 0) * 66];
    scn[t] = Xq[(t * 64 + 1) * 66];
  }

  #pragma unroll 1
  for (int a = 0; a < 64; a += 2) {
    {  // even: compute a, prefetch a+2
      half8 sv[NT];
      #pragma unroll
      for (int t = 0; t < NT; ++t) sv[t] = splat8(sc[t]);
      if (a + 2 < 64) {
        #pragma unroll
        for (int t = 0; t < NT; ++t) sc[t] = Xq[(t * 64 + a + 2) * 66];
      }
      #pragma unroll
      for (int ks = 0; ks < 4; ++ks) {
        half8 tb = sv[0] * x2r[0][ks];
        if (NT > 1) tb += sv[1] * x2r[1][ks];
        if (NT > 2) tb += sv[2] * x2r[2][ks];
        acc0 = __builtin_amdgcn_mfma_f32_32x32x16_f16(afE[0][ks], tb, acc0, 0, 0, 0);
        acc1 = __builtin_amdgcn_mfma_f32_32x32x16_f16(afE[1][ks], tb, acc1, 0, 0, 0);
      }
      if (a + 2 < 64) {
        const _Float16* wn = Wq + (a + 2) * 4096;
        #pragma unroll
        for (int ks = 0; ks < 4; ++ks) {
          afE[0][ks] = *(const half8*)(wn + ks * 1024);
          afE[1][ks] = *(const half8*)(wn + ks * 1024 + 512);
        }
      }
    }
    {  // odd: compute a+1, prefetch a+3
      half8 sv[NT];
      #pragma unroll
      for (int t = 0; t < NT; ++t) sv[t] = splat8(scn[t]);
      if (a + 3 < 64) {
        #pragma unroll
        for (int t = 0; t < NT; ++t) scn[t] = Xq[(t * 64 + a + 3) * 66];
      }
      #pragma unroll
      for (int ks = 0; ks < 4; ++ks) {
        half8 tb = sv[0] * x2r[0][ks];
        if (NT > 1) tb += sv[1] * x2r[1][ks];
        if (NT > 2) tb += sv[2] * x2r[2][ks];
        acc0 = __builtin_amdgcn_mfma_f32_32x32x16_f16(afO[0][ks], tb, acc0, 0, 0, 0);
        acc1 = __builtin_amdgcn_mfma_f32_32x32x16_f16(afO[1][ks], tb, acc1, 0, 0, 0);
      }
      if (a + 3 < 64) {
        const _Float16* wn = Wq + (a + 3) * 4096;
        #pragma unroll
        for (int ks = 0; ks < 4; ++ks) {
          afO[0][ks] = *(const half8*)(wn + ks * 1024);
          afO[1][ks] = *(const half8*)(wn + ks * 1024 + 512);
        }
      }
    }
  }
}

__global__ __launch_bounds__(128, 2) void tp_kernel(
    const float* __restrict__ x1, const float* __restrict__ x2,
    const _Float16* __restrict__ Wh, float* __restrict__ out,
    float* __restrict__ part)
{
  __shared__ __align__(16) _Float16 XS2[3 * 64 * 72]; // 27648 B
  __shared__ __align__(16) _Float16 XS1[3 * 64 * 66]; // 25344 B
  __shared__ Chunk chs[7];
  __shared__ int nch_s;

  const int tid  = threadIdx.x;
  const int slot = blockIdx.y;           // 0: L0; 1..3: L1 m; 4..12: L2 (u,v)
  const int q    = blockIdx.z;           // K-split quarter
  const int nsplit = gridDim.z;
  const int zbase = blockIdx.x * ZT;
  const int zgrp = tid >> 6;             // wave = z-group
  const int lane = tid & 63;
  const int ln31 = lane & 31;
  const int hf   = lane >> 5;
  const int zl   = zgrp * 32 + ln31;     // B-frag col z within tile

  int offO, dO, mO;
  if (slot == 0)      { offO = 0;   dO = 1; mO = 0; }
  else if (slot < 4)  { offO = 64;  dO = 3; mO = slot - 1; }
  else                { offO = 256; dO = 9; mO = slot - 4; }

  if (tid == 0) {
    int n = 0;
    auto add = [&](int p, int L1, int L2,
                   int i0, int i1, int i2, int j0, int j1, int j2,
                   float s0, float s1, float s2, int nt) {
      const int offs[3] = {0, 64, 256};
      const int ds[3]   = {1, 3, 9};
      Chunk c;
      c.wbase = p * 262144;
      c.o1[0] = offs[L1] + i0; c.o1[1] = offs[L1] + i1; c.o1[2] = offs[L1] + i2;
      c.o2[0] = offs[L2] + j0; c.o2[1] = offs[L2] + j1; c.o2[2] = offs[L2] + j2;
      c.sg[0] = s0; c.sg[1] = s1; c.sg[2] = s2;
      c.d1 = ds[L1]; c.d2 = ds[L2]; c.nt = nt;
      chs[n++] = c;
    };
    if (slot == 0) {
      add(0, 0,0, 0,0,0, 0,0,0, 1,0,0, 1);                  // A0*B0
      add(5, 1,1, 0,1,2, 0,1,2, 1,1,1, 3);                  // sum_e A1[e]B1[e]
      add(13,2,2, 0,1,2, 0,1,2, 1,1,1, 3);                  // sum_g A2[g]B2[g] (3 chunks)
      add(13,2,2, 3,4,5, 3,4,5, 1,1,1, 3);
      add(13,2,2, 6,7,8, 6,7,8, 1,1,1, 3);
    } else if (slot < 4) {
      const int m = slot - 1, p1 = (m+1)%3, p2 = (m+2)%3;
      add(1, 0,1, 0,0,0, m,0,0, 1,0,0, 1);                  // A0*B1[m]
      add(3, 1,0, m,0,0, 0,0,0, 1,0,0, 1);                  // A1[m]*B0
      add(6, 1,1, p1,p2,0, p2,p1,0, 1,-1,0, 2);             // eps(m,x,y)A1[x]B1[y]
      add(7, 1,2, 0,1,2, 3*m,3*m+1,3*m+2, 1,1,1, 3);        // sum_e A1[e]B2[m,e]
      add(10,2,1, 3*m,3*m+1,3*m+2, 0,1,2, 1,1,1, 3);        // sum_e A2[m,e]B1[e]
      add(14,2,2, 3*p1,3*p1+1,3*p1+2, 3*p2,3*p2+1,3*p2+2, 1,1,1, 3);    // +A2[p1,e]B2[p2,e]
      add(14,2,2, 3*p2,3*p2+1,3*p2+2, 3*p1,3*p1+1,3*p1+2, -1,-1,-1, 3); // -A2[p2,e]B2[p1,e]
    } else {
      const int m = slot - 4, u = m/3, v = m%3, q1 = (v+1)%3, q2 = (v+2)%3;
      add(2, 0,2, 0,0,0, m,0,0, 1,0,0, 1);                  // A0*B2[u,v]
      add(4, 1,1, u,0,0, v,0,0, 1,0,0, 1);                  // A1[u]*B1[v]
      add(8, 1,2, q1,q2,0, 3*u+q2,3*u+q1,0, 1,-1,0, 2);     // eps(v,x,y)A1[x]B2[u,y]
      add(9, 2,0, m,0,0, 0,0,0, 1,0,0, 1);                  // A2[u,v]*B0
      add(11,2,1, 3*u+q1,3*u+q2,0, q2,q1,0, 1,-1,0, 2);     // eps(v,e,f)A2[u,e]B1[f]
      add(12,2,2, 3*u,3*u+1,3*u+2, 3*v,3*v+1,3*v+2, 1,1,1, 3); // sum_e A2[u,e]B2[v,e]
    }
    nch_s = n;
  }
  __syncthreads();
  const int nch = nch_s;

  floatx16 acc0, acc1;
  #pragma unroll
  for (int r = 0; r < 16; ++r) { acc0[r] = 0.0f; acc1[r] = 0.0f; }

  for (int ci = q; ci < nch; ci += nsplit) {
    const Chunk C = chs[ci];  // block-uniform
    if (C.nt == 1)      run_chunk<1>(C, zbase, zl, hf, lane, tid, x1, x2, Wh, XS2, XS1, acc0, acc1);
    else if (C.nt == 2) run_chunk<2>(C, zbase, zl, hf, lane, tid, x1, x2, Wh, XS2, XS1, acc0, acc1);
    else                run_chunk<3>(C, zbase, zl, hf, lane, tid, x1, x2, Wh, XS2, XS1, acc0, acc1);
  }

  // epilogue: C/D 32x32 layout: col(z)=lane&31, row(c)=(r&3)+8*(r>>2)+4*(lane>>5).
  if (q == 0) {
    float* __restrict__ op = out + (size_t)(zbase + zl) * FEAT + offO + mO;
    #pragma unroll
    for (int r = 0; r < 16; ++r) {
      const int cr = (r & 3) + 8 * (r >> 2) + 4 * hf;
      op[(size_t)cr * dO]        = acc0[r];
      op[(size_t)(cr + 32) * dO] = acc1[r];
    }
  } else {
    // slot-major transposed plane: part[q-1][slot][c][z], lanes contiguous in z
    float* __restrict__ op = part + (size_t)(q - 1) * 3407872
                                  + (size_t)slot * 262144 + (zbase + zl);
    #pragma unroll
    for (int r = 0; r < 16; ++r) {
      const int cr = (r & 3) + 8 * (r >> 2) + 4 * hf;
      op[(size_t)cr * 4096]        = acc0[r];
      op[(size_t)(cr + 32) * 4096] = acc1[r];
    }
  }
}

extern "C" void kernel_launch(void* const* d_in, const int* in_sizes, int n_in,
                              void* d_out, int out_size, void* d_ws, size_t ws_size,
                              hipStream_t stream) {
  const float* x1 = (const float*)d_in[0];
  const float* x2 = (const float*)d_in[1];
  const float* w  = (const float*)d_in[2];
  float* out = (float*)d_out;
  _Float16* Wh = (_Float16*)d_ws;            // 15*64*4096 f16 = 7,864,320 B (swizzled)
  float* part = (float*)((char*)d_ws + 7864320);  // np planes x 13.63 MB f32

  // dynamic K-split: as many partial planes as d_ws can hold (1..3), +1 direct
  const size_t plane_bytes = 3407872ull * 4ull;
  int np = (ws_size > 7864320) ? (int)((ws_size - 7864320) / plane_bytes) : 1;
  if (np > 3) np = 3;
  if (np < 1) np = 1;
  const int nsplit = np + 1;

  const int nchunks = 15 * 64 * 4096 / 8;    // 491520 half8 chunks
  hipLaunchKernelGGL(swz_w_kernel, dim3(nchunks / 256), dim3(256), 0, stream, w, Wh);

  dim3 grid(64, 13, nsplit);  // z-tiles x slots x K-split
  hipLaunchKernelGGL(tp_kernel, grid, dim3(128), 0, stream, x1, x2, Wh, out, part);

  dim3 ggrid(64, 13);         // z-tiles x f-tiles
  hipLaunchKernelGGL(gather_kernel, ggrid, dim3(256), 0, stream, out, part, np);
}